// Round 5
// baseline (209.185 us; speedup 1.0000x reference)
//
#include <hip/hip_runtime.h>

#define ROI 31
#define HALF 15
#define H_DIM 256
#define W_DIM 256
#define C_DIM 32
#define TS 32          // input tile edge (px)
#define NTILE 1024     // 16 images * 8 * 8 tiles
#define LISTCAP 80     // max ROIs per tile list (avg ~15, Poisson; 80 is ~impossible to hit)

typedef float vfloat4 __attribute__((ext_vector_type(4)));

// ws layout: [0..NTILE) counts, [NTILE ..) lists[NTILE][LISTCAP]

__global__ __launch_bounds__(1024) void init_counts_kernel(int* __restrict__ counts) {
    counts[threadIdx.x] = 0;
}

// Each ROI registers itself with the <=4 input tiles its window intersects.
__global__ __launch_bounds__(256) void build_lists_kernel(
    const int* __restrict__ centers, int* __restrict__ counts,
    int* __restrict__ lists, int N)
{
    const int n = blockIdx.x * 256 + threadIdx.x;
    if (n >= N) return;
    const int b = centers[3 * n + 0];
    const int y = centers[3 * n + 1];
    const int x = centers[3 * n + 2];
    const int ty0 = max(y - HALF, 0) >> 5, ty1 = min(y + HALF, H_DIM - 1) >> 5;
    const int tx0 = max(x - HALF, 0) >> 5, tx1 = min(x + HALF, W_DIM - 1) >> 5;
    for (int ty = ty0; ty <= ty1; ++ty)
        for (int tx = tx0; tx <= tx1; ++tx) {
            const int tile = (b << 6) | (ty << 3) | tx;
            const int pos = atomicAdd(&counts[tile], 1);
            if (pos < LISTCAP) lists[tile * LISTCAP + pos] = n;
        }
}

// One block per input tile: read the 128 KB tile (HBM once, then L1/L2-hot),
// scatter intersection rectangles into each registered ROI's output slot.
__global__ __launch_bounds__(256) void scatter_extract_kernel(
    const float* __restrict__ poses, const int* __restrict__ centers,
    const int* __restrict__ counts, const int* __restrict__ lists,
    float* __restrict__ out)
{
    const int tile = blockIdx.x;
    const int b  = tile >> 6;
    const int ty = (tile >> 3) & 7;
    const int tx = tile & 7;
    const int cnt = min(counts[tile], LISTCAP);

    const int t  = threadIdx.x;
    const int pc = t >> 3;          // pixel-column within intersection (0..31)
    const int q  = t & 7;           // float4 index within pixel

    const int rowT0 = ty << 5, colT0 = tx << 5;
    const float* img = poses + (size_t)b * H_DIM * W_DIM * C_DIM;

    for (int j = 0; j < cnt; ++j) {
        const int n = lists[tile * LISTCAP + j];
        const int y = centers[3 * n + 1];
        const int x = centers[3 * n + 2];
        // intersection of ROI window with this tile (always non-empty)
        const int r0 = max(rowT0, y - HALF), r1 = min(rowT0 + TS - 1, y + HALF);
        const int c0 = max(colT0, x - HALF), c1 = min(colT0 + TS - 1, x + HALF);
        const int nc = c1 - c0 + 1;
        if (pc >= nc) continue;
        const int cc = c0 + pc;

        const float* src = img + ((size_t)r0 * W_DIM + cc) * C_DIM + q * 4;
        float* dst = out + ((size_t)n * ROI * ROI
                        + (size_t)(r0 - (y - HALF)) * ROI
                        + (size_t)(cc - (x - HALF))) * C_DIM + q * 4;

        for (int rr = r0; rr <= r1; ++rr) {
            vfloat4 v = *reinterpret_cast<const vfloat4*>(src);
            __builtin_nontemporal_store(v, reinterpret_cast<vfloat4*>(dst));
            src += (size_t)W_DIM * C_DIM;   // next input row
            dst += (size_t)ROI * C_DIM;     // next output row
        }
    }
}

// Zero the out-of-bounds fringe of border ROIs (~3% of output volume).
__global__ __launch_bounds__(256) void zero_oob_kernel(
    const int* __restrict__ centers, float* __restrict__ out)
{
    const int n = blockIdx.x;
    const int y = centers[3 * n + 1];
    const int x = centers[3 * n + 2];
    // fully interior -> nothing OOB
    if (y >= HALF && y <= H_DIM - 1 - HALF && x >= HALF && x <= W_DIM - 1 - HALF)
        return;

    const int t = threadIdx.x;
    if (t >= ROI * (C_DIM / 4)) return;   // 248 active
    const int c = t >> 3;
    const int q = t & 7;
    const int cc = x + c - HALF;
    const bool cok = (cc >= 0) && (cc < W_DIM);

    const vfloat4 z = (vfloat4)0.0f;
    for (int r = 0; r < ROI; ++r) {
        const int rr = y + r - HALF;
        const bool ok = cok && (rr >= 0) && (rr < H_DIM);
        if (!ok) {
            vfloat4* dst = reinterpret_cast<vfloat4*>(
                out + (((size_t)n * ROI + r) * ROI + c) * C_DIM) + q;
            __builtin_nontemporal_store(z, dst);
        }
    }
}

extern "C" void kernel_launch(void* const* d_in, const int* in_sizes, int n_in,
                              void* d_out, int out_size, void* d_ws, size_t ws_size,
                              hipStream_t stream) {
    const float* poses   = (const float*)d_in[0];
    const int*   centers = (const int*)d_in[1];
    float*       out     = (float*)d_out;

    int* counts = (int*)d_ws;            // NTILE ints
    int* lists  = counts + NTILE;        // NTILE * LISTCAP ints (~320 KB)

    const int N = in_sizes[1] / 3;

    init_counts_kernel<<<dim3(1), dim3(1024), 0, stream>>>(counts);
    build_lists_kernel<<<dim3((N + 255) / 256), dim3(256), 0, stream>>>(centers, counts, lists, N);
    scatter_extract_kernel<<<dim3(NTILE), dim3(256), 0, stream>>>(poses, centers, counts, lists, out);
    zero_oob_kernel<<<dim3(N), dim3(256), 0, stream>>>(centers, out);
}

// Round 6
// 169.854 us; speedup vs baseline: 1.2316x; 1.2316x over previous
//
#include <hip/hip_runtime.h>

#define ROI 31
#define HALF 15
#define H_DIM 256
#define W_DIM 256
#define C_DIM 32
#define TS 32
#define NTILE 1024     // 16 images * 8x8 tiles
#define LISTCAP 64     // slots per tile (Poisson mean ~15; P(>64) ~ 0)

typedef float vfloat4 __attribute__((ext_vector_type(4)));

__global__ __launch_bounds__(1024) void init_counts_kernel(int* __restrict__ counts) {
    counts[threadIdx.x] = 0;
}

// Each ROI registers itself with the <=4 input tiles its window intersects.
__global__ __launch_bounds__(256) void build_lists_kernel(
    const int* __restrict__ centers, int* __restrict__ counts,
    int* __restrict__ lists, int N)
{
    const int n = blockIdx.x * 256 + threadIdx.x;
    if (n >= N) return;
    const int b = centers[3 * n + 0];
    const int y = centers[3 * n + 1];
    const int x = centers[3 * n + 2];
    const int ty0 = max(y - HALF, 0) >> 5, ty1 = min(y + HALF, H_DIM - 1) >> 5;
    const int tx0 = max(x - HALF, 0) >> 5, tx1 = min(x + HALF, W_DIM - 1) >> 5;
    for (int ty = ty0; ty <= ty1; ++ty)
        for (int tx = tx0; tx <= tx1; ++tx) {
            const int tile = (b << 6) | (ty << 3) | tx;
            const int pos = atomicAdd(&counts[tile], 1);
            if (pos < LISTCAP) lists[tile * LISTCAP + pos] = n;
        }
}

// One block per (tile, slot): copy one ROI∩tile rectangle.
// blockIdx.x = slot (fast-varying -> same-tile blocks dispatch adjacently),
// blockIdx.y = tile.
__global__ __launch_bounds__(256) void scatter_extract_kernel(
    const float* __restrict__ poses, const int* __restrict__ centers,
    const int* __restrict__ counts, const int* __restrict__ lists,
    float* __restrict__ out)
{
    const int tile = blockIdx.y;
    const int slot = blockIdx.x;
    if (slot >= min(counts[tile], LISTCAP)) return;

    const int b  = tile >> 6;
    const int ty = (tile >> 3) & 7;
    const int tx = tile & 7;
    const int n  = lists[tile * LISTCAP + slot];

    const int y = centers[3 * n + 1];
    const int x = centers[3 * n + 2];

    const int rowT0 = ty << 5, colT0 = tx << 5;
    // intersection of ROI window with this tile (non-empty by construction)
    const int r0 = max(rowT0, y - HALF), r1 = min(rowT0 + TS - 1, y + HALF);
    const int c0 = max(colT0, x - HALF), c1 = min(colT0 + TS - 1, x + HALF);
    const int nc = c1 - c0 + 1;

    const int t  = threadIdx.x;
    const int pc = t >> 3;          // column within intersection
    const int q  = t & 7;           // float4 index within pixel
    if (pc >= nc) return;
    const int cc = c0 + pc;

    const float* src = poses + ((size_t)b * H_DIM * W_DIM
                              + (size_t)r0 * W_DIM + cc) * C_DIM + q * 4;
    float* dst = out + ((size_t)n * ROI * ROI
                      + (size_t)(r0 - (y - HALF)) * ROI
                      + (size_t)(cc - (x - HALF))) * C_DIM + q * 4;

    for (int rr = r0; rr <= r1; ++rr) {
        vfloat4 v = *reinterpret_cast<const vfloat4*>(src);
        __builtin_nontemporal_store(v, reinterpret_cast<vfloat4*>(dst));
        src += (size_t)W_DIM * C_DIM;
        dst += (size_t)ROI * C_DIM;
    }
}

// Zero the out-of-bounds fringe of border ROIs (~3% of output volume).
__global__ __launch_bounds__(256) void zero_oob_kernel(
    const int* __restrict__ centers, float* __restrict__ out)
{
    const int n = blockIdx.x;
    const int y = centers[3 * n + 1];
    const int x = centers[3 * n + 2];
    if (y >= HALF && y <= H_DIM - 1 - HALF && x >= HALF && x <= W_DIM - 1 - HALF)
        return;   // fully interior

    const int t = threadIdx.x;
    if (t >= ROI * (C_DIM / 4)) return;   // 248 active
    const int c = t >> 3;
    const int q = t & 7;
    const int cc = x + c - HALF;
    const bool cok = (cc >= 0) && (cc < W_DIM);

    const vfloat4 z = (vfloat4)0.0f;
    for (int r = 0; r < ROI; ++r) {
        const int rr = y + r - HALF;
        const bool ok = cok && (rr >= 0) && (rr < H_DIM);
        if (!ok) {
            vfloat4* dst = reinterpret_cast<vfloat4*>(
                out + (((size_t)n * ROI + r) * ROI + c) * C_DIM) + q;
            __builtin_nontemporal_store(z, dst);
        }
    }
}

extern "C" void kernel_launch(void* const* d_in, const int* in_sizes, int n_in,
                              void* d_out, int out_size, void* d_ws, size_t ws_size,
                              hipStream_t stream) {
    const float* poses   = (const float*)d_in[0];
    const int*   centers = (const int*)d_in[1];
    float*       out     = (float*)d_out;

    int* counts = (int*)d_ws;            // NTILE ints
    int* lists  = counts + NTILE;        // NTILE * LISTCAP ints

    const int N = in_sizes[1] / 3;

    init_counts_kernel<<<dim3(1), dim3(1024), 0, stream>>>(counts);
    build_lists_kernel<<<dim3((N + 255) / 256), dim3(256), 0, stream>>>(centers, counts, lists, N);
    scatter_extract_kernel<<<dim3(LISTCAP, NTILE), dim3(256), 0, stream>>>(poses, centers, counts, lists, out);
    zero_oob_kernel<<<dim3(N), dim3(256), 0, stream>>>(centers, out);
}

// Round 7
// 137.806 us; speedup vs baseline: 1.5180x; 1.2326x over previous
//
#include <hip/hip_runtime.h>

#define ROI 31
#define HALF 15
#define H_DIM 256
#define W_DIM 256
#define C_DIM 32
#define NSTRIP (16 * H_DIM)   // (image, row) strips = 4096
#define CAP 96                // ROIs per strip list; lambda=31, 96 ~ 11 sigma

typedef float vfloat4 __attribute__((ext_vector_type(4)));

__global__ __launch_bounds__(1024) void init_counts_kernel(int* __restrict__ counts) {
    const int i = blockIdx.x * 1024 + threadIdx.x;
    if (i < NSTRIP) counts[i] = 0;
}

// Each ROI registers with every (image,row) strip its window covers (<=31).
__global__ __launch_bounds__(256) void build_lists_kernel(
    const int* __restrict__ centers, int* __restrict__ counts,
    int* __restrict__ lists, int N)
{
    const int n = blockIdx.x * 256 + threadIdx.x;
    if (n >= N) return;
    const int b = centers[3 * n + 0];
    const int y = centers[3 * n + 1];
    const int r0 = max(y - HALF, 0), r1 = min(y + HALF, H_DIM - 1);
    for (int rr = r0; rr <= r1; ++rr) {
        const int strip = (b << 8) | rr;
        const int pos = atomicAdd(&counts[strip], 1);
        if (pos < CAP) lists[strip * CAP + pos] = n;
    }
}

// One block per image row: stage the row in LDS (each input line read from
// HBM exactly once, globally), then serve all ROI rows sourced from it.
__global__ __launch_bounds__(256) void strip_scatter_kernel(
    const float* __restrict__ poses, const int* __restrict__ centers,
    const int* __restrict__ counts, const int* __restrict__ lists,
    float* __restrict__ out)
{
    __shared__ vfloat4 row_lds[W_DIM * C_DIM / 4];   // 32 KB: [256 px][8 quads]

    const int strip = blockIdx.x;
    const int b  = strip >> 8;
    const int rr = strip & (H_DIM - 1);
    const int t  = threadIdx.x;

    // stage 32 KB row: 8 block-wide vfloat4 iterations, fully coalesced
    const vfloat4* src_row = reinterpret_cast<const vfloat4*>(
        poses + ((size_t)b * H_DIM + rr) * W_DIM * C_DIM);
    #pragma unroll
    for (int i = 0; i < 8; ++i)
        row_lds[i * 256 + t] = src_row[i * 256 + t];
    __syncthreads();

    const int cnt = min(counts[strip], CAP);
    const int pc = t >> 3;          // output column candidate 0..30
    const int q  = t & 7;           // float4 quad within pixel
    if (pc >= ROI) return;          // 248 active lanes

    for (int j = 0; j < cnt; ++j) {
        const int n = lists[strip * CAP + j];
        const int y = centers[3 * n + 1];
        const int x = centers[3 * n + 2];
        const int c0 = max(x - HALF, 0), c1 = min(x + HALF, W_DIM - 1);
        const int nc = c1 - c0 + 1;
        const int r  = rr - (y - HALF);      // output row 0..30 (in range by construction)
        if (pc < nc) {
            const int cc = c0 + pc;          // source column
            const int oc = cc - (x - HALF);  // output column
            vfloat4 v = row_lds[cc * 8 + q]; // lane-contiguous: conflict-free
            float* dst = out + (((size_t)n * ROI + r) * ROI + oc) * C_DIM + q * 4;
            __builtin_nontemporal_store(v, reinterpret_cast<vfloat4*>(dst));
        }
    }
}

// Zero the out-of-bounds fringe of border ROIs (disjoint from scatter writes).
__global__ __launch_bounds__(256) void zero_oob_kernel(
    const int* __restrict__ centers, float* __restrict__ out)
{
    const int n = blockIdx.x;
    const int y = centers[3 * n + 1];
    const int x = centers[3 * n + 2];
    if (y >= HALF && y <= H_DIM - 1 - HALF && x >= HALF && x <= W_DIM - 1 - HALF)
        return;   // fully interior

    const int t = threadIdx.x;
    if (t >= ROI * (C_DIM / 4)) return;   // 248 active
    const int c = t >> 3;
    const int q = t & 7;
    const int cc = x + c - HALF;
    const bool cok = (cc >= 0) && (cc < W_DIM);

    const vfloat4 z = (vfloat4)0.0f;
    for (int r = 0; r < ROI; ++r) {
        const int rr = y + r - HALF;
        const bool ok = cok && (rr >= 0) && (rr < H_DIM);
        if (!ok) {
            vfloat4* dst = reinterpret_cast<vfloat4*>(
                out + (((size_t)n * ROI + r) * ROI + c) * C_DIM) + q;
            __builtin_nontemporal_store(z, dst);
        }
    }
}

extern "C" void kernel_launch(void* const* d_in, const int* in_sizes, int n_in,
                              void* d_out, int out_size, void* d_ws, size_t ws_size,
                              hipStream_t stream) {
    const float* poses   = (const float*)d_in[0];
    const int*   centers = (const int*)d_in[1];
    float*       out     = (float*)d_out;

    int* counts = (int*)d_ws;            // NSTRIP ints
    int* lists  = counts + NSTRIP;       // NSTRIP * CAP ints (~1.5 MB)

    const int N = in_sizes[1] / 3;

    init_counts_kernel<<<dim3((NSTRIP + 1023) / 1024), dim3(1024), 0, stream>>>(counts);
    build_lists_kernel<<<dim3((N + 255) / 256), dim3(256), 0, stream>>>(centers, counts, lists, N);
    strip_scatter_kernel<<<dim3(NSTRIP), dim3(256), 0, stream>>>(poses, centers, counts, lists, out);
    zero_oob_kernel<<<dim3(N), dim3(256), 0, stream>>>(centers, out);
}

// Round 8
// 116.435 us; speedup vs baseline: 1.7966x; 1.1835x over previous
//
#include <hip/hip_runtime.h>

#define ROI 31
#define HALF 15
#define H_DIM 256
#define W_DIM 256
#define C_DIM 32
#define NBKT 4096        // (b<<8)|y buckets (B=16 * 256 rows)

typedef float vfloat4 __attribute__((ext_vector_type(4)));

// Single-block counting sort of ROIs by key=(b<<8)|y.
// Outputs: perm (sorted roi indices), off[NBKT+1] (bucket start offsets).
__global__ __launch_bounds__(1024) void sort_kernel(
    const int* __restrict__ centers, int* __restrict__ perm,
    int* __restrict__ off, int N)
{
    __shared__ int hist[NBKT];     // 16 KB
    __shared__ int base[NBKT];     // 16 KB
    __shared__ int partial[1024];  // 4 KB
    const int t = threadIdx.x;

    for (int k = t; k < NBKT; k += 1024) hist[k] = 0;
    __syncthreads();

    for (int i = t; i < N; i += 1024) {
        const int key = (centers[3 * i] << 8) | centers[3 * i + 1];
        atomicAdd(&hist[key], 1);
    }
    __syncthreads();

    // 4 buckets per thread -> scan 1024 partials -> per-bucket exclusive base
    const int s0 = hist[4 * t], s1 = hist[4 * t + 1];
    const int s2 = hist[4 * t + 2], s3 = hist[4 * t + 3];
    const int loc = s0 + s1 + s2 + s3;
    partial[t] = loc;
    __syncthreads();
    for (int o = 1; o < 1024; o <<= 1) {
        int v = (t >= o) ? partial[t - o] : 0;
        __syncthreads();
        partial[t] += v;
        __syncthreads();
    }
    const int ex = partial[t] - loc;
    base[4 * t]     = ex;
    base[4 * t + 1] = ex + s0;
    base[4 * t + 2] = ex + s0 + s1;
    base[4 * t + 3] = ex + s0 + s1 + s2;
    __syncthreads();

    for (int k = t; k < NBKT; k += 1024) off[k] = base[k];
    if (t == 0) off[NBKT] = N;
    for (int k = t; k < NBKT; k += 1024) hist[k] = 0;   // reuse as cursor
    __syncthreads();

    for (int i = t; i < N; i += 1024) {
        const int key = (centers[3 * i] << 8) | centers[3 * i + 1];
        const int pos = base[key] + atomicAdd(&hist[key], 1);
        perm[pos] = i;
    }
}

// One block per (image, row): stage the 32 KB row in LDS (each input line
// fetched from HBM exactly once globally), then write every ROI output row
// sourced from it — all 31 columns, zeros for OOB columns.
__global__ __launch_bounds__(256) void strip_scatter_kernel(
    const float* __restrict__ poses, const int* __restrict__ centers,
    const int* __restrict__ perm, const int* __restrict__ off,
    float* __restrict__ out)
{
    __shared__ vfloat4 row_lds[W_DIM * C_DIM / 4];   // 32 KB

    const int strip = blockIdx.x;
    const int b  = strip >> 8;
    const int rr = strip & (H_DIM - 1);
    const int t  = threadIdx.x;

    const vfloat4* src_row = reinterpret_cast<const vfloat4*>(
        poses + ((size_t)b * H_DIM + rr) * W_DIM * C_DIM);
    #pragma unroll
    for (int i = 0; i < 8; ++i)
        row_lds[i * 256 + t] = src_row[i * 256 + t];
    __syncthreads();

    // ROIs covering this row: y in [rr-15, rr+15] -> contiguous sorted range
    const int ylo = max(rr - HALF, 0), yhi = min(rr + HALF, H_DIM - 1);
    const int start = off[(b << 8) | ylo];
    const int end   = off[((b << 8) | yhi) + 1];

    const int pc = t >> 3;          // output column 0..30
    const int q  = t & 7;           // float4 quad within pixel
    if (pc >= ROI) return;          // 248 active lanes

    for (int pos = start; pos < end; ++pos) {
        const int n = perm[pos];
        const int y = centers[3 * n + 1];
        const int x = centers[3 * n + 2];
        const int r  = rr - (y - HALF);      // output row, 0..30 by construction
        const int cc = x - HALF + pc;        // source column for output col pc
        const bool cok = (cc >= 0) && (cc < W_DIM);
        const int ccc = min(max(cc, 0), W_DIM - 1);
        vfloat4 v = cok ? row_lds[ccc * 8 + q] : (vfloat4)0.0f;
        float* dst = out + (((size_t)n * ROI + r) * ROI + pc) * C_DIM + q * 4;
        __builtin_nontemporal_store(v, reinterpret_cast<vfloat4*>(dst));
    }
}

// Zero full output rows whose source row is out of bounds (y near 0 or H).
__global__ __launch_bounds__(256) void zero_rows_kernel(
    const int* __restrict__ centers, float* __restrict__ out)
{
    const int n = blockIdx.x;
    const int y = centers[3 * n + 1];
    if (y >= HALF && y <= H_DIM - 1 + HALF - ROI + 1) { /* fallthrough check below */ }
    const int t = threadIdx.x;
    if (t >= ROI * (C_DIM / 4)) return;   // 248 active
    const int pc = t >> 3;
    const int q  = t & 7;
    const vfloat4 z = (vfloat4)0.0f;

    // rows r with rr = y-15+r outside [0, H)
    const int rlo_end   = max(HALF - y, 0);                   // r in [0, rlo_end)
    const int rhi_start = min(H_DIM - 1 + HALF - y + 1, ROI); // r in [rhi_start, ROI)
    for (int r = 0; r < rlo_end; ++r) {
        float* dst = out + (((size_t)n * ROI + r) * ROI + pc) * C_DIM + q * 4;
        __builtin_nontemporal_store(z, reinterpret_cast<vfloat4*>(dst));
    }
    for (int r = rhi_start; r < ROI; ++r) {
        float* dst = out + (((size_t)n * ROI + r) * ROI + pc) * C_DIM + q * 4;
        __builtin_nontemporal_store(z, reinterpret_cast<vfloat4*>(dst));
    }
}

extern "C" void kernel_launch(void* const* d_in, const int* in_sizes, int n_in,
                              void* d_out, int out_size, void* d_ws, size_t ws_size,
                              hipStream_t stream) {
    const float* poses   = (const float*)d_in[0];
    const int*   centers = (const int*)d_in[1];
    float*       out     = (float*)d_out;

    const int N = in_sizes[1] / 3;
    const int B = in_sizes[0] / (H_DIM * W_DIM * C_DIM);

    int* perm = (int*)d_ws;          // N ints
    int* off  = perm + N;            // NBKT+1 ints

    sort_kernel<<<dim3(1), dim3(1024), 0, stream>>>(centers, perm, off, N);
    strip_scatter_kernel<<<dim3(B * H_DIM), dim3(256), 0, stream>>>(poses, centers, perm, off, out);
    zero_rows_kernel<<<dim3(N), dim3(256), 0, stream>>>(centers, out);
}

// Round 9
// 113.472 us; speedup vs baseline: 1.8435x; 1.0261x over previous
//
#include <hip/hip_runtime.h>

#define ROI 31
#define HALF 15
#define H_DIM 256
#define W_DIM 256
#define C_DIM 32
#define NBKT 4096               // (b<<8)|y buckets
#define VROWS (H_DIM + 2*HALF)  // 286 strip rows per image (incl. virtual OOB rows)

typedef float vfloat4 __attribute__((ext_vector_type(4)));

// Single-block counting sort by key=(b<<8)|y.
// Outputs packed records sorted[pos]=(n<<16)|(y<<8)|x and bucket offsets off[].
__global__ __launch_bounds__(1024) void sort_kernel(
    const int* __restrict__ centers, int* __restrict__ sorted,
    int* __restrict__ off, int N)
{
    __shared__ int hist[NBKT];     // 16 KB
    __shared__ int base[NBKT];     // 16 KB
    __shared__ int partial[1024];  // 4 KB
    const int t = threadIdx.x;

    for (int k = t; k < NBKT; k += 1024) hist[k] = 0;
    __syncthreads();

    for (int i = t; i < N; i += 1024) {
        const int key = (centers[3 * i] << 8) | centers[3 * i + 1];
        atomicAdd(&hist[key], 1);
    }
    __syncthreads();

    const int s0 = hist[4 * t], s1 = hist[4 * t + 1];
    const int s2 = hist[4 * t + 2], s3 = hist[4 * t + 3];
    const int loc = s0 + s1 + s2 + s3;
    partial[t] = loc;
    __syncthreads();
    for (int o = 1; o < 1024; o <<= 1) {
        int v = (t >= o) ? partial[t - o] : 0;
        __syncthreads();
        partial[t] += v;
        __syncthreads();
    }
    const int ex = partial[t] - loc;
    base[4 * t]     = ex;
    base[4 * t + 1] = ex + s0;
    base[4 * t + 2] = ex + s0 + s1;
    base[4 * t + 3] = ex + s0 + s1 + s2;
    __syncthreads();

    for (int k = t; k < NBKT; k += 1024) off[k] = base[k];
    if (t == 0) off[NBKT] = N;
    for (int k = t; k < NBKT; k += 1024) hist[k] = 0;   // reuse as cursor
    __syncthreads();

    for (int i = t; i < N; i += 1024) {
        const int b = centers[3 * i], y = centers[3 * i + 1], x = centers[3 * i + 2];
        const int key = (b << 8) | y;
        const int pos = base[key] + atomicAdd(&hist[key], 1);
        sorted[pos] = (i << 16) | (y << 8) | x;   // packed: one load per serve iter
    }
}

// One block per (image, virtual row rr in [-15,270]). Real rows stage 32 KB
// in LDS (each input line fetched from HBM exactly once globally) and serve
// all ROI rows sourced from them; virtual rows store zeros to the ROI rows
// they own. Every output element is written exactly once.
__global__ __launch_bounds__(256) void strip_scatter_kernel(
    const float* __restrict__ poses, const int* __restrict__ sorted,
    const int* __restrict__ off, float* __restrict__ out)
{
    __shared__ vfloat4 row_lds[W_DIM * C_DIM / 4];   // 32 KB

    const int strip = blockIdx.x;
    const int b  = strip / VROWS;
    const int rr = strip % VROWS - HALF;             // -15 .. 270
    const int t  = threadIdx.x;
    const bool real = ((unsigned)rr < (unsigned)H_DIM);

    if (real) {
        const vfloat4* src_row = reinterpret_cast<const vfloat4*>(
            poses + ((size_t)b * H_DIM + rr) * W_DIM * C_DIM);
        #pragma unroll
        for (int i = 0; i < 8; ++i)
            row_lds[i * 256 + t] = src_row[i * 256 + t];
        __syncthreads();
    }

    // ROIs whose window covers rr: y in [rr-15, rr+15] ∩ [0, H)
    const int ylo = max(rr - HALF, 0), yhi = min(rr + HALF, H_DIM - 1);
    const int start = off[(b << 8) | ylo];
    const int end   = off[((b << 8) | yhi) + 1];

    const int pc = t >> 3;          // output column 0..30
    const int q  = t & 7;           // float4 quad within pixel
    if (pc >= ROI) return;          // 248 active lanes

    for (int pos = start; pos < end; ++pos) {
        const int rec = sorted[pos];          // single uniform load
        const int n = rec >> 16;
        const int y = (rec >> 8) & 255;
        const int x = rec & 255;
        const int r  = rr - (y - HALF);       // output row 0..30 by construction
        const int cc = x - HALF + pc;         // source column for output col pc
        vfloat4 v = (vfloat4)0.0f;
        if (real) {
            const bool cok = (cc >= 0) && (cc < W_DIM);
            const int ccc = min(max(cc, 0), W_DIM - 1);
            if (cok) v = row_lds[ccc * 8 + q];
        }
        float* dst = out + (((size_t)n * ROI + r) * ROI + pc) * C_DIM + q * 4;
        __builtin_nontemporal_store(v, reinterpret_cast<vfloat4*>(dst));
    }
}

extern "C" void kernel_launch(void* const* d_in, const int* in_sizes, int n_in,
                              void* d_out, int out_size, void* d_ws, size_t ws_size,
                              hipStream_t stream) {
    const float* poses   = (const float*)d_in[0];
    const int*   centers = (const int*)d_in[1];
    float*       out     = (float*)d_out;

    const int N = in_sizes[1] / 3;
    const int B = in_sizes[0] / (H_DIM * W_DIM * C_DIM);

    int* sorted = (int*)d_ws;        // N ints
    int* off    = sorted + N;        // NBKT+1 ints

    sort_kernel<<<dim3(1), dim3(1024), 0, stream>>>(centers, sorted, off, N);
    strip_scatter_kernel<<<dim3(B * VROWS), dim3(256), 0, stream>>>(poses, sorted, off, out);
}

// Round 10
// 112.752 us; speedup vs baseline: 1.8553x; 1.0064x over previous
//
#include <hip/hip_runtime.h>

#define ROI 31
#define HALF 15
#define H_DIM 256
#define W_DIM 256
#define C_DIM 32
#define NBKT 4096               // (b<<8)|y buckets
#define VROWS (H_DIM + 2*HALF)  // 286 strip rows per image (incl. virtual OOB rows)

typedef float vfloat4 __attribute__((ext_vector_type(4)));

// Single-block counting sort by key=(b<<8)|y.
// Outputs packed records sorted[pos]=(n<<16)|(y<<8)|x and bucket offsets off[].
__global__ __launch_bounds__(1024) void sort_kernel(
    const int* __restrict__ centers, int* __restrict__ sorted,
    int* __restrict__ off, int N)
{
    __shared__ int hist[NBKT];     // 16 KB
    __shared__ int base[NBKT];     // 16 KB
    __shared__ int partial[1024];  // 4 KB
    const int t = threadIdx.x;

    for (int k = t; k < NBKT; k += 1024) hist[k] = 0;
    __syncthreads();

    for (int i = t; i < N; i += 1024) {
        const int key = (centers[3 * i] << 8) | centers[3 * i + 1];
        atomicAdd(&hist[key], 1);
    }
    __syncthreads();

    const int s0 = hist[4 * t], s1 = hist[4 * t + 1];
    const int s2 = hist[4 * t + 2], s3 = hist[4 * t + 3];
    const int loc = s0 + s1 + s2 + s3;
    partial[t] = loc;
    __syncthreads();
    for (int o = 1; o < 1024; o <<= 1) {
        int v = (t >= o) ? partial[t - o] : 0;
        __syncthreads();
        partial[t] += v;
        __syncthreads();
    }
    const int ex = partial[t] - loc;
    base[4 * t]     = ex;
    base[4 * t + 1] = ex + s0;
    base[4 * t + 2] = ex + s0 + s1;
    base[4 * t + 3] = ex + s0 + s1 + s2;
    __syncthreads();

    for (int k = t; k < NBKT; k += 1024) off[k] = base[k];
    if (t == 0) off[NBKT] = N;
    for (int k = t; k < NBKT; k += 1024) hist[k] = 0;   // reuse as cursor
    __syncthreads();

    for (int i = t; i < N; i += 1024) {
        const int b = centers[3 * i], y = centers[3 * i + 1], x = centers[3 * i + 2];
        const int key = (b << 8) | y;
        const int pos = base[key] + atomicAdd(&hist[key], 1);
        sorted[pos] = (i << 16) | (y << 8) | x;   // packed record
    }
}

// One block per (image, virtual row rr in [-15,270]). Real rows stage 32 KB
// in LDS (each input line fetched from HBM exactly once globally) and serve
// all ROI output rows sourced from them; virtual rows store zeros to the
// rows they own. Records are pre-loaded into a VGPR (lane l = record l) and
// broadcast per-iteration via readlane: no memory access in the serve loop
// except the LDS read and the NT store.
__global__ __launch_bounds__(256) void strip_scatter_kernel(
    const float* __restrict__ poses, const int* __restrict__ sorted,
    const int* __restrict__ off, float* __restrict__ out, int N)
{
    __shared__ vfloat4 row_lds[W_DIM * C_DIM / 4];   // 32 KB

    const int strip = blockIdx.x;
    const int b  = strip / VROWS;
    const int rr = strip % VROWS - HALF;             // -15 .. 270
    const int t  = threadIdx.x;
    const bool real = ((unsigned)rr < (unsigned)H_DIM);

    if (real) {
        const vfloat4* src_row = reinterpret_cast<const vfloat4*>(
            poses + ((size_t)b * H_DIM + rr) * W_DIM * C_DIM);
        #pragma unroll
        for (int i = 0; i < 8; ++i)
            row_lds[i * 256 + t] = src_row[i * 256 + t];
    }

    // ROIs whose window covers rr: y in [rr-15, rr+15] ∩ [0, H)
    const int ylo = max(rr - HALF, 0), yhi = min(rr + HALF, H_DIM - 1);
    const int start = off[(b << 8) | ylo];
    const int end   = off[((b << 8) | yhi) + 1];
    const int cnt   = end - start;

    // per-wave: lane l holds record start+l (guarded clamp; excess unused)
    const int lane = t & 63;
    const int recv = sorted[min(start + lane, N - 1)];

    if (real) __syncthreads();

    const int pc = t >> 3;          // output column 0..30
    const int q  = t & 7;           // float4 quad within pixel
    if (pc >= ROI) return;          // 248 active lanes

    const int m = min(cnt, 64);
    for (int j = 0; j < m; ++j) {
        const int rec = __builtin_amdgcn_readlane(recv, j);   // uniform, no mem
        const int n = rec >> 16;
        const int y = (rec >> 8) & 255;
        const int x = rec & 255;
        const int r  = rr - y + HALF;        // output row 0..30 by construction
        const int cc = x - HALF + pc;        // source column for output col pc
        vfloat4 v = (vfloat4)0.0f;
        if (real && cc >= 0 && cc < W_DIM)
            v = row_lds[cc * 8 + q];
        float* dst = out + (((size_t)n * ROI + r) * ROI + pc) * C_DIM + q * 4;
        __builtin_nontemporal_store(v, reinterpret_cast<vfloat4*>(dst));
    }
    // rare tail: more than 64 ROIs on one strip
    for (int j = 64; j < cnt; ++j) {
        const int rec = sorted[start + j];
        const int n = rec >> 16;
        const int y = (rec >> 8) & 255;
        const int x = rec & 255;
        const int r  = rr - y + HALF;
        const int cc = x - HALF + pc;
        vfloat4 v = (vfloat4)0.0f;
        if (real && cc >= 0 && cc < W_DIM)
            v = row_lds[cc * 8 + q];
        float* dst = out + (((size_t)n * ROI + r) * ROI + pc) * C_DIM + q * 4;
        __builtin_nontemporal_store(v, reinterpret_cast<vfloat4*>(dst));
    }
}

extern "C" void kernel_launch(void* const* d_in, const int* in_sizes, int n_in,
                              void* d_out, int out_size, void* d_ws, size_t ws_size,
                              hipStream_t stream) {
    const float* poses   = (const float*)d_in[0];
    const int*   centers = (const int*)d_in[1];
    float*       out     = (float*)d_out;

    const int N = in_sizes[1] / 3;
    const int B = in_sizes[0] / (H_DIM * W_DIM * C_DIM);

    int* sorted = (int*)d_ws;        // N ints
    int* off    = sorted + N;        // NBKT+1 ints

    sort_kernel<<<dim3(1), dim3(1024), 0, stream>>>(centers, sorted, off, N);
    strip_scatter_kernel<<<dim3(B * VROWS), dim3(256), 0, stream>>>(poses, sorted, off, out, N);
}